// Round 1
// 136.819 us; speedup vs baseline: 1.0250x; 1.0250x over previous
//
#include <hip/hip_runtime.h>

// B=32, S=127, new_seq=128, D=768, H=12, HD=64
#define NB 32
#define NS 128
#define SD 127
#define ND 768
#define NH 12
#define HD 64

__device__ inline float wredSum(float v){
  #pragma unroll
  for (int off=32; off>0; off>>=1) v += __shfl_xor(v, off);
  return v;
}
__device__ inline float wredMax(float v){
  #pragma unroll
  for (int off=32; off>0; off>>=1) v = fmaxf(v, __shfl_xor(v, off));
  return v;
}

// N0: fold uk (blk<144) + bkdot (blk 0) + ei rows (blk>=144)  [unchanged]
__global__ __launch_bounds__(256)
void fold_ei(const float* __restrict__ Wk, const float* __restrict__ bk,
             const float* __restrict__ desc, const float* __restrict__ Wa,
             float* __restrict__ uk, float* __restrict__ bkdot,
             float* __restrict__ ei){
  int blk = blockIdx.x, t = threadIdx.x;
  int wave = t >> 6, lane = t & 63;
  if (blk < 144){
    __shared__ float red[4][64];
    int h = blk/12, cb = blk%12;
    int c0 = t & 63, dg = t >> 6;
    const float* base = Wk + (size_t)(h*HD + dg*16)*ND + cb*64 + c0;
    float acc = 0.f;
    #pragma unroll
    for (int i=0;i<16;++i) acc += base[(size_t)i*ND] * Wa[64 + dg*16 + i];
    red[dg][c0] = acc;
    __syncthreads();
    if (dg==0) uk[h*ND + cb*64 + c0] = red[0][c0]+red[1][c0]+red[2][c0]+red[3][c0];
    if (blk==0 && t < NH){
      float a = 0.f;
      for (int d=0; d<64; ++d) a += bk[t*HD+d]*Wa[64+d];
      bkdot[t] = a;
    }
  } else {
    int bs = blk - 144;                  // 0..4063
    int b = bs / SD, s = bs % SD;
    float wea = Wa[128 + lane];
    const float* row = desc + (size_t)bs * ND;
    #pragma unroll
    for (int hh=0; hh<3; ++hh){
      int h = wave + hh*4;
      float v = row[h*HD + lane] * wea;
      v = wredSum(v);
      if (lane==0) ei[(size_t)(b*NH + h)*NS + s] = v;
    }
  }
}

// N1: lk rows. 1024 blocks x 4 rows; uk in 36 regs/lane; 12 indep wredSums.
// [unchanged]
__global__ __launch_bounds__(256)
void lk_kernel(const float* __restrict__ nv, const float* __restrict__ uk,
               const float* __restrict__ bkdot, float* __restrict__ lk){
  __shared__ __align__(16) float S[4*ND];
  int blk = blockIdx.x, t = threadIdx.x, wave = t>>6, lane = t&63;
  float ukr[3][12], bkd[3];
  #pragma unroll
  for (int hh=0; hh<3; ++hh){
    int h = wave*3 + hh;
    bkd[hh] = bkdot[h];
    #pragma unroll
    for (int k=0;k<12;++k) ukr[hh][k] = uk[h*ND + lane + 64*k];
  }
  int j0 = blk*4;                        // 4 rows, same b (128 | 4)
  const float4* src = (const float4*)(nv + (size_t)j0*ND);
  ((float4*)S)[t]     = src[t];
  ((float4*)S)[t+256] = src[t+256];
  ((float4*)S)[t+512] = src[t+512];
  __syncthreads();
  float acc[12];
  #pragma unroll
  for (int rr=0; rr<4; ++rr)
    #pragma unroll
    for (int hh=0; hh<3; ++hh){
      float a = 0.f;
      #pragma unroll
      for (int k=0;k<12;++k) a += S[rr*ND + lane + 64*k]*ukr[hh][k];
      acc[rr*3+hh] = a;
    }
  #pragma unroll
  for (int i=0;i<12;++i) acc[i] = wredSum(acc[i]);
  if (lane == 0){
    int b = j0 >> 7, jb = j0 & 127;
    #pragma unroll
    for (int rr=0; rr<4; ++rr)
      #pragma unroll
      for (int hh=0; hh<3; ++hh)
        lk[(size_t)(b*NH + wave*3 + hh)*NS + jb + rr] = acc[rr*3+hh] + bkd[hh];
  }
}

// N2 (new): fused softmax + j-weighted nv sum + V-proj + both output writes.
// One block per (b,h). Only 2 distinct attention rows per (b,h) exist
// (row 0 and rows 1..127), so the weighted sum fits in-block:
// 192 threads x float4 covers all 768 d with 2 accumulators each.
// No m_part round-trip (saves 75.5 MB HBM vs the split version).
// XCD swizzle: blockIdx i -> XCD i%8; map so each XCD owns 4 consecutive b
// (all 12 heads co-located => nv[b] L2-resident for the x12 re-read).
__global__ __launch_bounds__(256)
void attn_fused(const float* __restrict__ nv, const float* __restrict__ lk,
                const float* __restrict__ ei, const float* __restrict__ Wv,
                const float* __restrict__ bv, float* __restrict__ out){
  int logical = ((blockIdx.x & 7) * 48) + (blockIdx.x >> 3);  // 384 = 8*48, bijective
  int b = logical / NH, h = logical % NH;
  int t = threadIdx.x, wave = t >> 6, lane = t & 63;
  __shared__ __align__(16) float slk[NS];
  __shared__ __align__(16) float sei0[NS];    // ei[b, h%6]
  __shared__ __align__(16) float sei1[NS];    // ei[b, h]
  __shared__ __align__(16) float wf0[NS];     // attn row 0
  __shared__ __align__(16) float wf1[NS];     // attn rows 1..127
  __shared__ __align__(16) float msum0[ND];
  __shared__ __align__(16) float msum1[ND];
  __shared__ __align__(16) float cvec0[HD];
  __shared__ __align__(16) float cvec1[HD];

  if (t < NS) slk[t] = lk[(size_t)(b*NH + h)*NS + t];
  if (t < SD) sei0[t] = ei[(size_t)(b*NH + (h % 6))*NS + t];
  if (t >= 128 && t < 128 + SD) sei1[t-128] = ei[(size_t)(b*NH + h)*NS + (t-128)];
  __syncthreads();

  // 2-row softmax: wave 0 -> row 0 (e_cls = le_i[h%6], always on),
  //                wave 1 -> rows>=1 (le_j gate: only heads 6..11)
  if (wave < 2){
    const float* eir = (wave==0) ? sei0 : sei1;
    float g = (wave==0) ? 1.f : (h >= 6 ? 1.f : 0.f);
    float x0 = (lane>=1) ? slk[lane] + g*eir[lane-1] : -3.0e38f;
    float x1 = slk[lane+64] + g*eir[lane+63];
    float mm = wredMax(fmaxf(x0,x1));
    float e0 = (lane>=1) ? __expf(x0-mm) : 0.f;   // col 0 masked -> exactly 0
    float e1 = __expf(x1-mm);
    float s  = wredSum(e0+e1);
    float inv = 1.f/s;
    float* wf = (wave==0) ? wf0 : wf1;
    wf[lane]    = e0*inv;
    wf[lane+64] = e1*inv;
  }
  __syncthreads();

  if (wave < 3){
    // weighted sum over j: thread t owns float4 chunk t of 192 (=768 d)
    const float4* nvb = (const float4*)(nv + (size_t)b*NS*ND);
    float4 a0 = make_float4(0.f,0.f,0.f,0.f);
    float4 a1 = make_float4(0.f,0.f,0.f,0.f);
    #pragma unroll 4
    for (int j=1; j<NS; ++j){                 // wf*[0]==0: col 0 contributes nothing
      float4 x = nvb[(size_t)j*192 + t];
      float w0 = wf0[j], w1 = wf1[j];         // LDS broadcast, conflict-free
      a0.x += w0*x.x; a0.y += w0*x.y; a0.z += w0*x.z; a0.w += w0*x.w;
      a1.x += w1*x.x; a1.y += w1*x.y; a1.z += w1*x.z; a1.w += w1*x.w;
    }
    ((float4*)msum0)[t] = a0;
    ((float4*)msum1)[t] = a1;
  } else {
    // wave 3 overlaps the attn-tile write (64 KB) with the weighted sum
    float4* abase = (float4*)(out + (size_t)NB*NS*ND + (size_t)(b*NH + h)*NS*NS);
    const float4* w0v = (const float4*)wf0;
    const float4* w1v = (const float4*)wf1;
    #pragma unroll
    for (int k=0; k<64; ++k){
      int idx = lane + k*64;                  // 0..4095, fully linear/coalesced
      int q = idx & 31;
      abase[idx] = (idx < 32) ? w0v[q] : w1v[q];   // row 0 vs rows 1..127
    }
  }
  __syncthreads();

  // V-projection: ctx = Wv_h . msum (+bv; attn rows sum to 1)
  const float* wvh = Wv + (size_t)h*HD*ND;
  #pragma unroll
  for (int dd=0; dd<16; ++dd){
    int d = wave*16 + dd;
    const float* wvr = wvh + (size_t)d*ND;
    float p0=0.f, p1=0.f;
    #pragma unroll
    for (int k=0; k<12; ++k){
      float wv = wvr[lane + 64*k];
      p0 += wv*msum0[lane + 64*k];
      p1 += wv*msum1[lane + 64*k];
    }
    p0 = wredSum(p0); p1 = wredSum(p1);
    if (lane==0){
      float bb = bv[h*HD + d];
      cvec0[d] = p0 + bb;
      cvec1[d] = p1 + bb;
    }
  }
  __syncthreads();

  // basis write: row 0 = cvec0, rows 1..127 = cvec1 (2048 float4)
  float* bo = out + (size_t)b*NS*ND + h*HD;
  const float4* c0 = (const float4*)cvec0;
  const float4* c1 = (const float4*)cvec1;
  #pragma unroll
  for (int k=0; k<8; ++k){
    int idx = t + k*256;
    int i = idx >> 4, q = idx & 15;
    *(float4*)(bo + (size_t)i*ND + q*4) = (i==0) ? c0[q] : c1[q];
  }
}

extern "C" void kernel_launch(void* const* d_in, const int* in_sizes, int n_in,
                              void* d_out, int out_size, void* d_ws, size_t ws_size,
                              hipStream_t stream) {
  const float* desc = (const float*)d_in[0];
  const float* nv   = (const float*)d_in[1];
  // d_in[2]=Wq, d_in[3]=bq: unused (softmax shift-invariance)
  const float* Wk   = (const float*)d_in[4];
  const float* bk   = (const float*)d_in[5];
  const float* Wv   = (const float*)d_in[6];
  const float* bv   = (const float*)d_in[7];
  const float* Wa   = (const float*)d_in[8];
  // d_in[9]=ba: unused (constant shift)
  float* out = (float*)d_out;
  float* ws  = (float*)d_ws;

  float* uk     = ws;               // 9216
  float* bkdot  = ws + 9216;        // 16
  float* eibuf  = ws + 9232;        // 49152
  float* lkbuf  = ws + 58384;       // 49152
  // m_part eliminated

  fold_ei   <<<4208, 256, 0, stream>>>(Wk, bk, desc, Wa, uk, bkdot, eibuf);
  lk_kernel <<<1024, 256, 0, stream>>>(nv, uk, bkdot, lkbuf);
  attn_fused<<<384,  256, 0, stream>>>(nv, lkbuf, eibuf, Wv, bv, out);
}

// Round 2
// 127.209 us; speedup vs baseline: 1.1025x; 1.0755x over previous
//
#include <hip/hip_runtime.h>

// B=32, S=127, new_seq=128, D=768, H=12, HD=64
#define NB 32
#define NS 128
#define SD 127
#define ND 768
#define NH 12
#define HD 64

__device__ inline float wredSum(float v){
  #pragma unroll
  for (int off=32; off>0; off>>=1) v += __shfl_xor(v, off);
  return v;
}
__device__ inline float wredMax(float v){
  #pragma unroll
  for (int off=32; off>0; off>>=1) v = fmaxf(v, __shfl_xor(v, off));
  return v;
}

// K0: uk = fold of Wk rows with wk_a (144 blocks) + bkdot (blk 0)
__global__ __launch_bounds__(256)
void fold_uk(const float* __restrict__ Wk, const float* __restrict__ bk,
             const float* __restrict__ Wa, float* __restrict__ uk,
             float* __restrict__ bkdot){
  int blk = blockIdx.x, t = threadIdx.x;
  __shared__ float red[4][64];
  int h = blk/12, cb = blk%12;
  int c0 = t & 63, dg = t >> 6;
  const float* base = Wk + (size_t)(h*HD + dg*16)*ND + cb*64 + c0;
  float acc = 0.f;
  #pragma unroll
  for (int i=0;i<16;++i) acc += base[(size_t)i*ND] * Wa[64 + dg*16 + i];
  red[dg][c0] = acc;
  __syncthreads();
  if (dg==0) uk[h*ND + cb*64 + c0] = red[0][c0]+red[1][c0]+red[2][c0]+red[3][c0];
  if (blk==0 && t < NH){
    float a = 0.f;
    for (int d=0; d<64; ++d) a += bk[t*HD+d]*Wa[64+d];
    bkdot[t] = a;
  }
}

// K1: fused lk rows (blk<1024, unchanged math) + ei rows (blk>=1024, 4 rows
// per block, float4 loads, 16-lane-group reduces).
__global__ __launch_bounds__(256)
void lk_ei(const float* __restrict__ nv, const float* __restrict__ uk,
           const float* __restrict__ bkdot, const float* __restrict__ Wa,
           const float* __restrict__ desc, float* __restrict__ lk,
           float* __restrict__ ei){
  int blk = blockIdx.x, t = threadIdx.x, wave = t>>6, lane = t&63;
  if (blk < 1024){
    __shared__ __align__(16) float S[4*ND];
    float ukr[3][12], bkd[3];
    #pragma unroll
    for (int hh=0; hh<3; ++hh){
      int h = wave*3 + hh;
      bkd[hh] = bkdot[h];
      #pragma unroll
      for (int k=0;k<12;++k) ukr[hh][k] = uk[h*ND + lane + 64*k];
    }
    int j0 = blk*4;                        // 4 rows, same b (128 | 4)
    const float4* src = (const float4*)(nv + (size_t)j0*ND);
    ((float4*)S)[t]     = src[t];
    ((float4*)S)[t+256] = src[t+256];
    ((float4*)S)[t+512] = src[t+512];
    __syncthreads();
    float acc[12];
    #pragma unroll
    for (int rr=0; rr<4; ++rr)
      #pragma unroll
      for (int hh=0; hh<3; ++hh){
        float a = 0.f;
        #pragma unroll
        for (int k=0;k<12;++k) a += S[rr*ND + lane + 64*k]*ukr[hh][k];
        acc[rr*3+hh] = a;
      }
    #pragma unroll
    for (int i=0;i<12;++i) acc[i] = wredSum(acc[i]);
    if (lane == 0){
      int b = j0 >> 7, jb = j0 & 127;
      #pragma unroll
      for (int rr=0; rr<4; ++rr)
        #pragma unroll
        for (int hh=0; hh<3; ++hh)
          lk[(size_t)(b*NH + wave*3 + hh)*NS + jb + rr] = acc[rr*3+hh] + bkd[hh];
    }
  } else {
    // ei: wave handles one desc row bs; f4 chunk i = lane+64c -> head i>>4,
    // within-chunk f4 pos = lane&15 (same for all c).
    int bs = (blk - 1024)*4 + wave;        // 0..4063
    int b = bs / SD, s = bs % SD;
    const float4* row = (const float4*)(desc + (size_t)bs*ND);
    float4 r0 = row[lane], r1 = row[lane+64], r2 = row[lane+128];
    float4 wa4 = ((const float4*)(Wa + 128))[lane & 15];
    float p0 = r0.x*wa4.x + r0.y*wa4.y + r0.z*wa4.z + r0.w*wa4.w;
    float p1 = r1.x*wa4.x + r1.y*wa4.y + r1.z*wa4.z + r1.w*wa4.w;
    float p2 = r2.x*wa4.x + r2.y*wa4.y + r2.z*wa4.z + r2.w*wa4.w;
    #pragma unroll
    for (int off=1; off<16; off<<=1){
      p0 += __shfl_xor(p0, off);
      p1 += __shfl_xor(p1, off);
      p2 += __shfl_xor(p2, off);
    }
    if ((lane & 15) == 0){
      int hb = lane >> 4;
      float* er = ei + (size_t)b*NH*NS + s;
      er[(size_t)(hb    )*NS] = p0;
      er[(size_t)(hb + 4)*NS] = p1;
      er[(size_t)(hb + 8)*NS] = p2;
    }
  }
}

// K2: fused softmax + 4-wave j-weighted nv sum + attn write + V-proj + basis.
// One block per (b,h); XCD swizzle co-locates all 12 heads of 4 b's per XCD
// so nv[b] (393 KB) is L2-resident for the x12 re-read.
__global__ __launch_bounds__(256)
void attn_fused(const float* __restrict__ nv, const float* __restrict__ lk,
                const float* __restrict__ ei, const float* __restrict__ Wv,
                const float* __restrict__ bv, float* __restrict__ out){
  int logical = ((blockIdx.x & 7) * 48) + (blockIdx.x >> 3);  // 384 = 8*48
  int b = logical / NH, h = logical % NH;
  int t = threadIdx.x, wave = t >> 6, lane = t & 63;
  __shared__ float slk[NS];
  __shared__ float sei0[NS];                  // ei[b, h%6]
  __shared__ float sei1[NS];                  // ei[b, h]
  __shared__ __align__(16) float wf0[NS];     // attn row 0
  __shared__ __align__(16) float wf1[NS];     // attn rows 1..127
  __shared__ __align__(16) float part[4][2][ND];  // per-wave j-sum partials
  __shared__ __align__(16) float msum0[ND];
  __shared__ __align__(16) float msum1[ND];
  __shared__ float cvec0[HD];
  __shared__ float cvec1[HD];

  if (t < NS) slk[t] = lk[(size_t)(b*NH + h)*NS + t];
  if (t < SD) sei0[t] = ei[(size_t)(b*NH + (h % 6))*NS + t];
  if (t >= 128 && t < 128 + SD) sei1[t-128] = ei[(size_t)(b*NH + h)*NS + (t-128)];
  __syncthreads();

  // 2-row softmax: wave 0 -> row 0 (e_cls = le_i[h%6], always on),
  //                wave 1 -> rows>=1 (le_j gate: only heads 6..11)
  if (wave < 2){
    const float* eir = (wave==0) ? sei0 : sei1;
    float g = (wave==0) ? 1.f : (h >= 6 ? 1.f : 0.f);
    float x0 = (lane>=1) ? slk[lane] + g*eir[lane-1] : -3.0e38f;
    float x1 = slk[lane+64] + g*eir[lane+63];
    float mm = wredMax(fmaxf(x0,x1));
    float e0 = (lane>=1) ? __expf(x0-mm) : 0.f;   // col 0 masked -> exactly 0
    float e1 = __expf(x1-mm);
    float s  = wredSum(e0+e1);
    float inv = 1.f/s;
    float* wf = (wave==0) ? wf0 : wf1;
    wf[lane]    = e0*inv;
    wf[lane+64] = e1*inv;
  }
  __syncthreads();

  // 4-wave j-sum: wave w owns j in [w*32, w*32+32); wf*[0]==0 so j=0 is inert.
  {
    const float4* nvb = (const float4*)(nv + (size_t)b*NS*ND)
                      + (size_t)(wave*32)*192;
    float4 a0[3], a1[3];
    #pragma unroll
    for (int c=0;c<3;++c){
      a0[c] = make_float4(0.f,0.f,0.f,0.f);
      a1[c] = make_float4(0.f,0.f,0.f,0.f);
    }
    #pragma unroll 4
    for (int jj=0; jj<32; ++jj){
      float w0 = wf0[wave*32 + jj], w1 = wf1[wave*32 + jj];  // LDS broadcast
      #pragma unroll
      for (int c=0;c<3;++c){
        float4 x = nvb[(size_t)jj*192 + lane + 64*c];
        a0[c].x += w0*x.x; a0[c].y += w0*x.y; a0[c].z += w0*x.z; a0[c].w += w0*x.w;
        a1[c].x += w1*x.x; a1[c].y += w1*x.y; a1[c].z += w1*x.z; a1[c].w += w1*x.w;
      }
    }
    #pragma unroll
    for (int c=0;c<3;++c){
      ((float4*)part[wave][0])[lane + 64*c] = a0[c];
      ((float4*)part[wave][1])[lane + 64*c] = a1[c];
    }
  }

  // attn tile write: 4096 float4, all 256 threads, fire-and-forget; stores
  // ack at L2 and the HBM drain overlaps the reduce + V-proj below.
  {
    float4* abase = (float4*)(out + (size_t)NB*NS*ND + (size_t)(b*NH + h)*NS*NS);
    const float4* w0v = (const float4*)wf0;
    const float4* w1v = (const float4*)wf1;
    #pragma unroll
    for (int k=0; k<16; ++k){
      int idx = t + k*256;                  // 0..4095, linear/coalesced
      int q = idx & 31;
      abase[idx] = (idx < 32) ? w0v[q] : w1v[q];   // row 0 vs rows 1..127
    }
  }
  __syncthreads();

  // cross-wave reduce of partials
  if (t < 192){
    float4 s0 = make_float4(0.f,0.f,0.f,0.f);
    float4 s1 = make_float4(0.f,0.f,0.f,0.f);
    #pragma unroll
    for (int w=0; w<4; ++w){
      float4 v0 = ((const float4*)part[w][0])[t];
      float4 v1 = ((const float4*)part[w][1])[t];
      s0.x += v0.x; s0.y += v0.y; s0.z += v0.z; s0.w += v0.w;
      s1.x += v1.x; s1.y += v1.y; s1.z += v1.z; s1.w += v1.w;
    }
    ((float4*)msum0)[t] = s0;
    ((float4*)msum1)[t] = s1;
  }
  __syncthreads();

  // V-projection: ctx = Wv_h . msum (+bv; attn rows sum to 1)
  const float* wvh = Wv + (size_t)h*HD*ND;
  #pragma unroll
  for (int dd=0; dd<16; ++dd){
    int d = wave*16 + dd;
    const float* wvr = wvh + (size_t)d*ND;
    float p0=0.f, p1=0.f;
    #pragma unroll
    for (int k=0; k<12; ++k){
      float wv = wvr[lane + 64*k];
      p0 += wv*msum0[lane + 64*k];
      p1 += wv*msum1[lane + 64*k];
    }
    p0 = wredSum(p0); p1 = wredSum(p1);
    if (lane==0){
      float bb = bv[h*HD + d];
      cvec0[d] = p0 + bb;
      cvec1[d] = p1 + bb;
    }
  }
  __syncthreads();

  // basis write: row 0 = cvec0, rows 1..127 = cvec1 (2048 float4)
  float* bo = out + (size_t)b*NS*ND + h*HD;
  const float4* c0 = (const float4*)cvec0;
  const float4* c1 = (const float4*)cvec1;
  #pragma unroll
  for (int k=0; k<8; ++k){
    int idx = t + k*256;
    int i = idx >> 4, q = idx & 15;
    *(float4*)(bo + (size_t)i*ND + q*4) = (i==0) ? c0[q] : c1[q];
  }
}

extern "C" void kernel_launch(void* const* d_in, const int* in_sizes, int n_in,
                              void* d_out, int out_size, void* d_ws, size_t ws_size,
                              hipStream_t stream) {
  const float* desc = (const float*)d_in[0];
  const float* nv   = (const float*)d_in[1];
  // d_in[2]=Wq, d_in[3]=bq: unused (softmax shift-invariance)
  const float* Wk   = (const float*)d_in[4];
  const float* bk   = (const float*)d_in[5];
  const float* Wv   = (const float*)d_in[6];
  const float* bv   = (const float*)d_in[7];
  const float* Wa   = (const float*)d_in[8];
  // d_in[9]=ba: unused (constant shift)
  float* out = (float*)d_out;
  float* ws  = (float*)d_ws;

  float* uk     = ws;               // 9216
  float* bkdot  = ws + 9216;        // 16
  float* eibuf  = ws + 9232;        // 49152
  float* lkbuf  = ws + 58384;       // 49152

  fold_uk   <<<144,  256, 0, stream>>>(Wk, bk, Wa, uk, bkdot);
  lk_ei     <<<2040, 256, 0, stream>>>(nv, uk, bkdot, Wa, desc, lkbuf, eibuf);
  attn_fused<<<384,  256, 0, stream>>>(nv, lkbuf, eibuf, Wv, bv, out);
}

// Round 3
// 126.681 us; speedup vs baseline: 1.1071x; 1.0042x over previous
//
#include <hip/hip_runtime.h>

// B=32, S=127, new_seq=128, D=768, H=12, HD=64
#define NB 32
#define NS 128
#define SD 127
#define ND 768
#define NH 12
#define HD 64

__device__ inline float wredSum(float v){
  #pragma unroll
  for (int off=32; off>0; off>>=1) v += __shfl_xor(v, off);
  return v;
}
__device__ inline float wredMax(float v){
  #pragma unroll
  for (int off=32; off>0; off>>=1) v = fmaxf(v, __shfl_xor(v, off));
  return v;
}

// K0: fold_uk (blocks 0..143) + bkdot (blk 0) + ei rows (blocks 144..1159).
// ei has no dependency on uk, so running it here fills the machine during
// the 144-block fold stage (previously 56% of CUs sat idle).
__global__ __launch_bounds__(256)
void fold_ei2(const float* __restrict__ Wk, const float* __restrict__ bk,
              const float* __restrict__ desc, const float* __restrict__ Wa,
              float* __restrict__ uk, float* __restrict__ bkdot,
              float* __restrict__ ei){
  int blk = blockIdx.x, t = threadIdx.x, wave = t >> 6, lane = t & 63;
  if (blk < 144){
    __shared__ float red[4][64];
    int h = blk/12, cb = blk%12;
    int c0 = t & 63, dg = t >> 6;
    const float* base = Wk + (size_t)(h*HD + dg*16)*ND + cb*64 + c0;
    float acc = 0.f;
    #pragma unroll
    for (int i=0;i<16;++i) acc += base[(size_t)i*ND] * Wa[64 + dg*16 + i];
    red[dg][c0] = acc;
    __syncthreads();
    if (dg==0) uk[h*ND + cb*64 + c0] = red[0][c0]+red[1][c0]+red[2][c0]+red[3][c0];
    if (blk==0 && t < NH){
      float a = 0.f;
      for (int d=0; d<64; ++d) a += bk[t*HD+d]*Wa[64+d];
      bkdot[t] = a;
    }
  } else {
    // ei: wave handles one desc row bs; f4 chunk i = lane+64c -> head i>>4,
    // within-chunk f4 pos = lane&15 (same for all c).
    int bs = (blk - 144)*4 + wave;         // 0..4063
    int b = bs / SD, s = bs % SD;
    const float4* row = (const float4*)(desc + (size_t)bs*ND);
    float4 r0 = row[lane], r1 = row[lane+64], r2 = row[lane+128];
    float4 wa4 = ((const float4*)(Wa + 128))[lane & 15];
    float p0 = r0.x*wa4.x + r0.y*wa4.y + r0.z*wa4.z + r0.w*wa4.w;
    float p1 = r1.x*wa4.x + r1.y*wa4.y + r1.z*wa4.z + r1.w*wa4.w;
    float p2 = r2.x*wa4.x + r2.y*wa4.y + r2.z*wa4.z + r2.w*wa4.w;
    #pragma unroll
    for (int off=1; off<16; off<<=1){
      p0 += __shfl_xor(p0, off);
      p1 += __shfl_xor(p1, off);
      p2 += __shfl_xor(p2, off);
    }
    if ((lane & 15) == 0){
      int hb = lane >> 4;
      float* er = ei + (size_t)b*NH*NS + s;
      er[(size_t)(hb    )*NS] = p0;
      er[(size_t)(hb + 4)*NS] = p1;
      er[(size_t)(hb + 8)*NS] = p2;
    }
  }
}

// K1: lk rows only. 1024 blocks x 4 rows; uk in 36 regs/lane; 12 wredSums.
__global__ __launch_bounds__(256)
void lk_kernel(const float* __restrict__ nv, const float* __restrict__ uk,
               const float* __restrict__ bkdot, float* __restrict__ lk){
  __shared__ __align__(16) float S[4*ND];
  int blk = blockIdx.x, t = threadIdx.x, wave = t>>6, lane = t&63;
  float ukr[3][12], bkd[3];
  #pragma unroll
  for (int hh=0; hh<3; ++hh){
    int h = wave*3 + hh;
    bkd[hh] = bkdot[h];
    #pragma unroll
    for (int k=0;k<12;++k) ukr[hh][k] = uk[h*ND + lane + 64*k];
  }
  int j0 = blk*4;                        // 4 rows, same b (128 | 4)
  const float4* src = (const float4*)(nv + (size_t)j0*ND);
  ((float4*)S)[t]     = src[t];
  ((float4*)S)[t+256] = src[t+256];
  ((float4*)S)[t+512] = src[t+512];
  __syncthreads();
  float acc[12];
  #pragma unroll
  for (int rr=0; rr<4; ++rr)
    #pragma unroll
    for (int hh=0; hh<3; ++hh){
      float a = 0.f;
      #pragma unroll
      for (int k=0;k<12;++k) a += S[rr*ND + lane + 64*k]*ukr[hh][k];
      acc[rr*3+hh] = a;
    }
  #pragma unroll
  for (int i=0;i<12;++i) acc[i] = wredSum(acc[i]);
  if (lane == 0){
    int b = j0 >> 7, jb = j0 & 127;
    #pragma unroll
    for (int rr=0; rr<4; ++rr)
      #pragma unroll
      for (int hh=0; hh<3; ++hh)
        lk[(size_t)(b*NH + wave*3 + hh)*NS + jb + rr] = acc[rr*3+hh] + bkd[hh];
  }
}

// K2: fused softmax + 4-wave j-weighted nv sum + attn write + V-proj + basis.
// One block per (b,h); XCD swizzle co-locates all 12 heads of 4 b's per XCD
// so nv[b] (393 KB) is L2-resident for the x12 re-read.
__global__ __launch_bounds__(256)
void attn_fused(const float* __restrict__ nv, const float* __restrict__ lk,
                const float* __restrict__ ei, const float* __restrict__ Wv,
                const float* __restrict__ bv, float* __restrict__ out){
  int logical = ((blockIdx.x & 7) * 48) + (blockIdx.x >> 3);  // 384 = 8*48
  int b = logical / NH, h = logical % NH;
  int t = threadIdx.x, wave = t >> 6, lane = t & 63;
  __shared__ float slk[NS];
  __shared__ float sei0[NS];                  // ei[b, h%6]
  __shared__ float sei1[NS];                  // ei[b, h]
  __shared__ __align__(16) float wf0[NS];     // attn row 0
  __shared__ __align__(16) float wf1[NS];     // attn rows 1..127
  __shared__ __align__(16) float part[4][2][ND];  // per-wave j-sum partials
  __shared__ __align__(16) float msum0[ND];
  __shared__ __align__(16) float msum1[ND];
  __shared__ float cvec0[HD];
  __shared__ float cvec1[HD];

  if (t < NS) slk[t] = lk[(size_t)(b*NH + h)*NS + t];
  if (t < SD) sei0[t] = ei[(size_t)(b*NH + (h % 6))*NS + t];
  if (t >= 128 && t < 128 + SD) sei1[t-128] = ei[(size_t)(b*NH + h)*NS + (t-128)];
  __syncthreads();

  // 2-row softmax: wave 0 -> row 0 (e_cls = le_i[h%6], always on),
  //                wave 1 -> rows>=1 (le_j gate: only heads 6..11)
  if (wave < 2){
    const float* eir = (wave==0) ? sei0 : sei1;
    float g = (wave==0) ? 1.f : (h >= 6 ? 1.f : 0.f);
    float x0 = (lane>=1) ? slk[lane] + g*eir[lane-1] : -3.0e38f;
    float x1 = slk[lane+64] + g*eir[lane+63];
    float mm = wredMax(fmaxf(x0,x1));
    float e0 = (lane>=1) ? __expf(x0-mm) : 0.f;   // col 0 masked -> exactly 0
    float e1 = __expf(x1-mm);
    float s  = wredSum(e0+e1);
    float inv = 1.f/s;
    float* wf = (wave==0) ? wf0 : wf1;
    wf[lane]    = e0*inv;
    wf[lane+64] = e1*inv;
  }
  __syncthreads();

  // 4-wave j-sum: wave w owns j in [w*32, w*32+32); wf*[0]==0 so j=0 is inert.
  {
    const float4* nvb = (const float4*)(nv + (size_t)b*NS*ND)
                      + (size_t)(wave*32)*192;
    float4 a0[3], a1[3];
    #pragma unroll
    for (int c=0;c<3;++c){
      a0[c] = make_float4(0.f,0.f,0.f,0.f);
      a1[c] = make_float4(0.f,0.f,0.f,0.f);
    }
    #pragma unroll 4
    for (int jj=0; jj<32; ++jj){
      float w0 = wf0[wave*32 + jj], w1 = wf1[wave*32 + jj];  // LDS broadcast
      #pragma unroll
      for (int c=0;c<3;++c){
        float4 x = nvb[(size_t)jj*192 + lane + 64*c];
        a0[c].x += w0*x.x; a0[c].y += w0*x.y; a0[c].z += w0*x.z; a0[c].w += w0*x.w;
        a1[c].x += w1*x.x; a1[c].y += w1*x.y; a1[c].z += w1*x.z; a1[c].w += w1*x.w;
      }
    }
    #pragma unroll
    for (int c=0;c<3;++c){
      ((float4*)part[wave][0])[lane + 64*c] = a0[c];
      ((float4*)part[wave][1])[lane + 64*c] = a1[c];
    }
  }

  // attn tile write: 4096 float4, all 256 threads, fire-and-forget; stores
  // ack at L2 and the drain overlaps the reduce + V-proj below.
  {
    float4* abase = (float4*)(out + (size_t)NB*NS*ND + (size_t)(b*NH + h)*NS*NS);
    const float4* w0v = (const float4*)wf0;
    const float4* w1v = (const float4*)wf1;
    #pragma unroll
    for (int k=0; k<16; ++k){
      int idx = t + k*256;                  // 0..4095, linear/coalesced
      int q = idx & 31;
      abase[idx] = (idx < 32) ? w0v[q] : w1v[q];   // row 0 vs rows 1..127
    }
  }
  __syncthreads();

  // cross-wave reduce of partials
  if (t < 192){
    float4 s0 = make_float4(0.f,0.f,0.f,0.f);
    float4 s1 = make_float4(0.f,0.f,0.f,0.f);
    #pragma unroll
    for (int w=0; w<4; ++w){
      float4 v0 = ((const float4*)part[w][0])[t];
      float4 v1 = ((const float4*)part[w][1])[t];
      s0.x += v0.x; s0.y += v0.y; s0.z += v0.z; s0.w += v0.w;
      s1.x += v1.x; s1.y += v1.y; s1.z += v1.z; s1.w += v1.w;
    }
    ((float4*)msum0)[t] = s0;
    ((float4*)msum1)[t] = s1;
  }
  __syncthreads();

  // V-projection: ctx = Wv_h . msum (+bv; attn rows sum to 1).
  // msum hoisted into 6 f4 regs once per wave; Wv rows read as coalesced
  // float4 (3 per lane per row) instead of 12 scalar loads per row.
  {
    const float4* ms0 = (const float4*)msum0;
    const float4* ms1 = (const float4*)msum1;
    float4 m0a = ms0[lane], m0b = ms0[lane+64], m0c = ms0[lane+128];
    float4 m1a = ms1[lane], m1b = ms1[lane+64], m1c = ms1[lane+128];
    const float* wvh = Wv + (size_t)h*HD*ND;
    #pragma unroll
    for (int dd=0; dd<16; ++dd){
      int d = wave*16 + dd;
      const float4* wv4 = (const float4*)(wvh + (size_t)d*ND);
      float4 wa = wv4[lane], wb = wv4[lane+64], wc = wv4[lane+128];
      float p0 = wa.x*m0a.x + wa.y*m0a.y + wa.z*m0a.z + wa.w*m0a.w
               + wb.x*m0b.x + wb.y*m0b.y + wb.z*m0b.z + wb.w*m0b.w
               + wc.x*m0c.x + wc.y*m0c.y + wc.z*m0c.z + wc.w*m0c.w;
      float p1 = wa.x*m1a.x + wa.y*m1a.y + wa.z*m1a.z + wa.w*m1a.w
               + wb.x*m1b.x + wb.y*m1b.y + wb.z*m1b.z + wb.w*m1b.w
               + wc.x*m1c.x + wc.y*m1c.y + wc.z*m1c.z + wc.w*m1c.w;
      p0 = wredSum(p0); p1 = wredSum(p1);
      if (lane==0){
        float bb = bv[h*HD + d];
        cvec0[d] = p0 + bb;
        cvec1[d] = p1 + bb;
      }
    }
  }
  __syncthreads();

  // basis write: row 0 = cvec0, rows 1..127 = cvec1 (2048 float4)
  float* bo = out + (size_t)b*NS*ND + h*HD;
  const float4* c0 = (const float4*)cvec0;
  const float4* c1 = (const float4*)cvec1;
  #pragma unroll
  for (int k=0; k<8; ++k){
    int idx = t + k*256;
    int i = idx >> 4, q = idx & 15;
    *(float4*)(bo + (size_t)i*ND + q*4) = (i==0) ? c0[q] : c1[q];
  }
}

extern "C" void kernel_launch(void* const* d_in, const int* in_sizes, int n_in,
                              void* d_out, int out_size, void* d_ws, size_t ws_size,
                              hipStream_t stream) {
  const float* desc = (const float*)d_in[0];
  const float* nv   = (const float*)d_in[1];
  // d_in[2]=Wq, d_in[3]=bq: unused (softmax shift-invariance)
  const float* Wk   = (const float*)d_in[4];
  const float* bk   = (const float*)d_in[5];
  const float* Wv   = (const float*)d_in[6];
  const float* bv   = (const float*)d_in[7];
  const float* Wa   = (const float*)d_in[8];
  // d_in[9]=ba: unused (constant shift)
  float* out = (float*)d_out;
  float* ws  = (float*)d_ws;

  float* uk     = ws;               // 9216
  float* bkdot  = ws + 9216;        // 16
  float* eibuf  = ws + 9232;        // 49152
  float* lkbuf  = ws + 58384;       // 49152

  fold_ei2  <<<1160, 256, 0, stream>>>(Wk, bk, desc, Wa, uk, bkdot, eibuf);
  lk_kernel <<<1024, 256, 0, stream>>>(nv, uk, bkdot, lkbuf);
  attn_fused<<<384,  256, 0, stream>>>(nv, lkbuf, eibuf, Wv, bv, out);
}